// Round 4
// baseline (641.916 us; speedup 1.0000x reference)
//
#include <hip/hip_runtime.h>
#include <hip/hip_cooperative_groups.h>

namespace cg = cooperative_groups;

#define C_GMS 0.0026f

// DPP wave shifts: full-rate VALU cross-lane, no LDS latency.
// from_left  = value of lane-1 (wave_shr:1, 0x138), lane 0 reads 0
// from_right = value of lane+1 (wave_shl:1, 0x130), lane 63 reads 0
__device__ __forceinline__ float dppL(float x) {
    return __int_as_float(__builtin_amdgcn_mov_dpp(__float_as_int(x), 0x138, 0xf, 0xf, true));
}
__device__ __forceinline__ float dppR(float x) {
    return __int_as_float(__builtin_amdgcn_mov_dpp(__float_as_int(x), 0x130, 0xf, 0xf, true));
}
__device__ __forceinline__ float med3f(float a, float b, float c) {
    return __builtin_amdgcn_fmed3f(a, b, c);   // exact median of 3 (no NaNs here)
}

// One wave owns a 64-col strip (60 output cols), rolls down RC output rows.
// All state in registers; cross-column via DPP. Zero LDS.
// median9 = med3(max3(col lows), med3(col meds), min3(col highs)) -- exact.
template<bool RGB, bool POOL>
__device__ __forceinline__ void gms_phase(
    int u, const float* __restrict__ srcX, const float* __restrict__ srcY,
    int H, int W, int nstrips, int nchunks, int RC,
    float* __restrict__ partial, float* __restrict__ dX, float* __restrict__ dY)
{
    const int nunits = 16 * nstrips * nchunks;
    if (u >= nunits) return;                    // wave-uniform
    const int lane = threadIdx.x & 63;

    const int s  = u % nstrips;                 // strip fastest: adjacent waves share halos
    const int t1 = u / nstrips;
    const int k  = t1 % nchunks;
    const int b  = t1 / nchunks;

    const int c0 = 60 * s - 1;
    const int c  = c0 + lane;                   // my gray column
    const int R0 = k * RC;                      // first output row (even)
    const int iend = min(R0 + RC, H - 2);

    const size_t HW = (size_t)H * W;
    const float* PX = srcX + (size_t)b * (RGB ? 3 * HW : HW);
    const float* PY = srcY + (size_t)b * (RGB ? 3 * HW : HW);
    const bool cok = (c >= 0) && (c < W);

    auto loadrow = [&](const float* __restrict__ P, int r) -> float {
        float v = 0.0f;
        if (r >= 0 && r < H) {                  // wave-uniform
            if (cok) {                          // per-lane zero-pad
                size_t o = (size_t)r * W + c;
                if (RGB) v = (P[o] + P[o + HW] + P[o + 2 * HW]) * (1.0f / 3.0f);
                else     v = P[o];
            }
        }
        return v;
    };

    // column triple sort + DPP combine; rs = 3-wide rowsum of medians (Gy)
    auto medrow = [&](float ga, float gb, float gc, float& m, float& rs) {
        float lo = fminf(fminf(ga, gb), gc);
        float me = med3f(ga, gb, gc);
        float hi = fmaxf(fmaxf(ga, gb), gc);
        float lmax = fmaxf(fmaxf(dppL(lo), lo), dppR(lo));
        float mid  = med3f(dppL(me), me, dppR(me));
        float hmin = fminf(fminf(dppL(hi), hi), dppR(hi));
        m  = med3f(lmax, mid, hmin);
        rs = m + dppL(m) + dppR(m);
    };

    const int Hd = H >> 1, Wd = W >> 1;
    const int phalf = R0 >> 1;
    const int pend  = min(phalf + (RC >> 1), Hd);
    const bool poolLane = ((lane & 1) == 1) && (lane <= 59) && (c + 1 < W);

    auto dopool = [&](float bx, float cx, float by, float cy, int p) {
        if (!POOL) return;
        if (p < phalf || p >= pend) return;     // uniform
        float ux = bx + cx, uy = by + cy;
        float hx = ux + dppR(ux);
        float hy = uy + dppR(uy);
        if (poolLane) {
            size_t o = ((size_t)b * Hd + p) * Wd + (c >> 1);
            dX[o] = hx * 0.25f;
            dY[o] = hy * 0.25f;
        }
    };

    // warmup: gray rows R0-1 .. R0+3 -> median rows R0..R0+2
    float xa = loadrow(PX, R0 - 1), ya = loadrow(PY, R0 - 1);
    float xb = loadrow(PX, R0),     yb = loadrow(PY, R0);
    float xc = loadrow(PX, R0 + 1), yc = loadrow(PY, R0 + 1);
    float xd = loadrow(PX, R0 + 2), yd = loadrow(PY, R0 + 2);
    float xe = loadrow(PX, R0 + 3), ye = loadrow(PY, R0 + 3);

    float mx0, mx1, mx2, rx0, rx1, rx2;
    float my0, my1, my2, ry0, ry1, ry2;
    medrow(xa, xb, xc, mx0, rx0); medrow(ya, yb, yc, my0, ry0);
    dopool(xb, xc, yb, yc, phalf);              // pool gray rows (R0, R0+1)
    medrow(xb, xc, xd, mx1, rx1); medrow(yb, yc, yd, my1, ry1);
    medrow(xc, xd, xe, mx2, rx2); medrow(yc, yd, ye, my2, ry2);

    float gx2 = xd, gx3 = xe, gy2 = yd, gy3 = ye; // gray rows i+2, i+3

    const bool outLane = (lane >= 2) && (lane <= 61) && (c <= W - 2);
    float acc = 0.0f;

    for (int i = R0; i < iend; ++i) {
        float nx = loadrow(PX, i + 4);          // prefetch next gray row
        float ny = loadrow(PY, i + 4);

        float csx = mx0 + mx1 + mx2;
        float csy = my0 + my1 + my2;
        float Gxx = dppR(csx) - dppL(csx);
        float Gxy = dppR(csy) - dppL(csy);
        float Gyx = rx0 - rx2;
        float Gyy = ry0 - ry2;
        float gI = sqrtf(Gxx * Gxx + Gyx * Gyx) * (1.0f / 3.0f);
        float gR = sqrtf(Gxy * Gxy + Gyy * Gyy) * (1.0f / 3.0f);
        float gmap = (2.0f * gI * gR + C_GMS) / (gI * gI + gR * gR + C_GMS);
        if (outLane) acc += 1.0f - gmap;

        if (((i + 3) & 1) == 1) dopool(gx2, gx3, gy2, gy3, (i + 2) >> 1);

        float mxn, rxn, myn, ryn;
        medrow(gx2, gx3, nx, mxn, rxn);
        medrow(gy2, gy3, ny, myn, ryn);
        mx0 = mx1; mx1 = mx2; mx2 = mxn; rx0 = rx1; rx1 = rx2; rx2 = rxn;
        my0 = my1; my1 = my2; my2 = myn; ry0 = ry1; ry1 = ry2; ry2 = ryn;
        gx2 = gx3; gx3 = nx; gy2 = gy3; gy3 = ny;
    }

    for (int off = 32; off; off >>= 1) acc += __shfl_down(acc, off, 64);
    if (lane == 0) partial[u] = acc;            // plain store, no atomics
}

// Everything in one cooperative kernel: 4 scales + finalize, grid.sync between.
// grid = 1152 blocks x 256 thr = 4608 waves = phase-0 unit count exactly.
__global__ __launch_bounds__(256, 5) void msgms_fused(
    const float* __restrict__ Ii, const float* __restrict__ Ir,
    float* __restrict__ P,
    float* __restrict__ X1, float* __restrict__ Y1,
    float* __restrict__ X2, float* __restrict__ Y2,
    float* __restrict__ X3, float* __restrict__ Y3,
    float* __restrict__ out)
{
    cg::grid_group grid = cg::this_grid();
    const int u = blockIdx.x * 4 + (threadIdx.x >> 6);
    __shared__ double wsum[4];

    //                      units: 16*strips*chunks
    gms_phase<true,  true >(u, Ii, Ir, 512, 512, 9, 32, 16, P,        X1, Y1); // 4608
    grid.sync();
    gms_phase<false, true >(u, X1, Y1, 256, 256, 5, 32,  8, P + 4608, X2, Y2); // 2560
    grid.sync();
    gms_phase<false, true >(u, X2, Y2, 128, 128, 3, 32,  4, P + 7168, X3, Y3); // 1536
    grid.sync();
    gms_phase<false, false>(u, X3, Y3,  64,  64, 2, 16,  4, P + 8704, nullptr, nullptr); // 512
    grid.sync();

    if (blockIdx.x == 0) {
        const int tid = threadIdx.x;
        const double w0 = 1.0 / (4.0 * 16.0 * 510.0 * 510.0);
        const double w1 = 1.0 / (4.0 * 16.0 * 254.0 * 254.0);
        const double w2 = 1.0 / (4.0 * 16.0 * 126.0 * 126.0);
        const double w3 = 1.0 / (4.0 * 16.0 * 62.0 * 62.0);
        double v = 0.0;
        for (int i = tid; i < 9216; i += 256) {
            double w = (i < 4608) ? w0 : (i < 7168) ? w1 : (i < 8704) ? w2 : w3;
            v += (double)P[i] * w;
        }
        for (int off = 32; off; off >>= 1) v += __shfl_down(v, off, 64);
        if ((tid & 63) == 0) wsum[tid >> 6] = v;
        __syncthreads();
        if (tid == 0) out[0] = (float)(wsum[0] + wsum[1] + wsum[2] + wsum[3]);
    }
}

extern "C" void kernel_launch(void* const* d_in, const int* in_sizes, int n_in,
                              void* d_out, int out_size, void* d_ws, size_t ws_size,
                              hipStream_t stream) {
    const float* Ii = (const float*)d_in[0];
    const float* Ir = (const float*)d_in[1];
    float* out = (float*)d_out;
    const int B = 16;

    char* ws = (char*)d_ws;
    float* P  = (float*)ws;                    // 9216 partials (pad to 16384)
    float* X1 = P + 16384;
    float* Y1 = X1 + B * 256 * 256;
    float* X2 = Y1 + B * 256 * 256;
    float* Y2 = X2 + B * 128 * 128;
    float* X3 = Y2 + B * 128 * 128;
    float* Y3 = X3 + B * 64 * 64;

    void* args[] = { (void*)&Ii, (void*)&Ir, (void*)&P,
                     (void*)&X1, (void*)&Y1, (void*)&X2, (void*)&Y2,
                     (void*)&X3, (void*)&Y3, (void*)&out };
    hipLaunchCooperativeKernel((const void*)msgms_fused, dim3(1152), dim3(256),
                               args, 0, stream);
}

// Round 5
// 165.904 us; speedup vs baseline: 3.8692x; 3.8692x over previous
//
#include <hip/hip_runtime.h>

#define C_GMS 0.0026f

// DPP wavefront shifts: full-rate VALU cross-lane, zero LDS latency.
// dppL = value of lane-1 (wf_shr:1, 0x138), lane 0 reads 0 (bound_ctrl)
// dppR = value of lane+1 (wf_shl:1, 0x130), lane 63 reads 0
__device__ __forceinline__ float dppL(float x) {
    return __int_as_float(__builtin_amdgcn_mov_dpp(__float_as_int(x), 0x138, 0xf, 0xf, true));
}
__device__ __forceinline__ float dppR(float x) {
    return __int_as_float(__builtin_amdgcn_mov_dpp(__float_as_int(x), 0x130, 0xf, 0xf, true));
}
__device__ __forceinline__ float med3f(float a, float b, float c) {
    return __builtin_amdgcn_fmed3f(a, b, c);   // exact median-of-3, 1 instr
}

// One wave owns a 64-col strip (60 output cols), rolls down RC output rows.
// All state in registers; cross-column via DPP. Zero LDS, zero atomics.
// median9 = med3(max3(col lows), med3(col meds), min3(col highs)) -- exact.
// Verified correct in R3/R4 (absmax = 0).
template<bool RGB, bool POOL, int RC>
__global__ __launch_bounds__(256) void gms_scale_kernel(
    const float* __restrict__ srcX, const float* __restrict__ srcY,
    int H, int W, int nstrips, int nchunks,
    float* __restrict__ partial,
    float* __restrict__ dX, float* __restrict__ dY)
{
    const int lane = threadIdx.x & 63;
    const int u = blockIdx.x * 4 + (threadIdx.x >> 6);

    const int s  = u % nstrips;        // strip fastest: adjacent waves share halos in L2
    const int t1 = u / nstrips;
    const int k  = t1 % nchunks;
    const int b  = t1 / nchunks;

    const int c0 = 60 * s - 1;
    const int c  = c0 + lane;          // my gray column
    const int R0 = k * RC;             // first output row (even)
    const int iend = min(R0 + RC, H - 2);

    const int HW = H * W;
    const float* PX = srcX + (size_t)b * (RGB ? 3 * HW : HW);
    const float* PY = srcY + (size_t)b * (RGB ? 3 * HW : HW);
    const bool cok = (c >= 0) && (c < W);

    // load gray row r of both images (RGB: channel mean); zero-pad OOB
    auto loadrow2 = [&](int r, float& vx, float& vy) {
        vx = 0.0f; vy = 0.0f;
        if (r >= 0 && r < H) {          // wave-uniform
            if (cok) {                  // per-lane (exec-masked loads)
                int o = r * W + c;
                if (RGB) {
                    vx = (PX[o] + PX[o + HW] + PX[o + 2 * HW]) * (1.0f / 3.0f);
                    vy = (PY[o] + PY[o + HW] + PY[o + 2 * HW]) * (1.0f / 3.0f);
                } else {
                    vx = PX[o];
                    vy = PY[o];
                }
            }
        }
    };

    // column triple sort + DPP combine; rs = 3-wide horiz sum of medians (Gy)
    auto medrow = [&](float ga, float gb, float gc, float& m, float& rs) {
        float lo = fminf(fminf(ga, gb), gc);
        float me = med3f(ga, gb, gc);
        float hi = fmaxf(fmaxf(ga, gb), gc);
        float lmax = fmaxf(fmaxf(dppL(lo), lo), dppR(lo));
        float mid  = med3f(dppL(me), me, dppR(me));
        float hmin = fminf(fminf(dppL(hi), hi), dppR(hi));
        m  = med3f(lmax, mid, hmin);
        rs = m + dppL(m) + dppR(m);
    };

    const int Hd = H >> 1, Wd = W >> 1;
    const int phalf = R0 >> 1;
    const int pend  = min(phalf + (RC >> 1), Hd);
    const bool poolLane = ((lane & 1) == 1) && (lane <= 59) && (c + 1 < W);

    // 2x2 avg-pool of gray rows (rb, rc) -> pooled row p (fused downsample)
    auto dopool = [&](float bx, float cx, float by, float cy, int p) {
        if (!POOL) return;
        if (p < phalf || p >= pend) return;   // uniform
        float ux = bx + cx, uy = by + cy;
        float hx = ux + dppR(ux);
        float hy = uy + dppR(uy);
        if (poolLane) {
            size_t o = ((size_t)b * Hd + p) * Wd + (c >> 1);
            dX[o] = hx * 0.25f;
            dY[o] = hy * 0.25f;
        }
    };

    // warmup: gray rows R0-1 .. R0+3 -> median rows R0..R0+2
    float xa, ya, xb, yb, xc, yc, xd, yd, xe, ye;
    loadrow2(R0 - 1, xa, ya);
    loadrow2(R0,     xb, yb);
    loadrow2(R0 + 1, xc, yc);
    loadrow2(R0 + 2, xd, yd);
    loadrow2(R0 + 3, xe, ye);

    float mx0, mx1, mx2, rx0, rx1, rx2;
    float my0, my1, my2, ry0, ry1, ry2;
    medrow(xa, xb, xc, mx0, rx0); medrow(ya, yb, yc, my0, ry0);
    dopool(xb, xc, yb, yc, phalf);             // pool gray rows (R0, R0+1)
    medrow(xb, xc, xd, mx1, rx1); medrow(yb, yc, yd, my1, ry1);
    medrow(xc, xd, xe, mx2, rx2); medrow(yc, yd, ye, my2, ry2);

    float gx2 = xd, gx3 = xe, gy2 = yd, gy3 = ye; // gray rows i+2, i+3

    const bool outLane = (lane >= 2) && (lane <= 61) && (c <= W - 2);
    float acc = 0.0f;

    for (int i = R0; i < iend; ++i) {
        float nx, ny;
        loadrow2(i + 4, nx, ny);               // prefetch next gray row

        // Prewitt + GMS for output row i (median rows i..i+2)
        float csx = mx0 + mx1 + mx2;
        float csy = my0 + my1 + my2;
        float Gxx = dppR(csx) - dppL(csx);
        float Gxy = dppR(csy) - dppL(csy);
        float Gyx = rx0 - rx2;
        float Gyy = ry0 - ry2;
        float gI = sqrtf(Gxx * Gxx + Gyx * Gyx) * (1.0f / 3.0f);
        float gR = sqrtf(Gxy * Gxy + Gyy * Gyy) * (1.0f / 3.0f);
        float gmap = (2.0f * gI * gR + C_GMS) / (gI * gI + gR * gR + C_GMS);
        if (outLane) acc += 1.0f - gmap;

        if (((i + 3) & 1) == 1) dopool(gx2, gx3, gy2, gy3, (i + 2) >> 1);

        // median row i+3 from gray rows i+2..i+4
        float mxn, rxn, myn, ryn;
        medrow(gx2, gx3, nx, mxn, rxn);
        medrow(gy2, gy3, ny, myn, ryn);
        mx0 = mx1; mx1 = mx2; mx2 = mxn; rx0 = rx1; rx1 = rx2; rx2 = rxn;
        my0 = my1; my1 = my2; my2 = myn; ry0 = ry1; ry1 = ry2; ry2 = ryn;
        gx2 = gx3; gx3 = nx; gy2 = gy3; gy3 = ny;
    }

    for (int off = 32; off; off >>= 1) acc += __shfl_down(acc, off, 64);
    if (lane == 0) partial[u] = acc;           // plain store, no atomics
}

__global__ __launch_bounds__(256) void finalize_kernel(
    const float* __restrict__ P, int n0, int n1, int n2, int n3,
    float* __restrict__ out)
{
    const int tid = threadIdx.x;
    const double w0 = 1.0 / (4.0 * 16.0 * 510.0 * 510.0);
    const double w1 = 1.0 / (4.0 * 16.0 * 254.0 * 254.0);
    const double w2 = 1.0 / (4.0 * 16.0 * 126.0 * 126.0);
    const double w3 = 1.0 / (4.0 * 16.0 * 62.0 * 62.0);
    const int e0 = n0, e1 = e0 + n1, e2 = e1 + n2, e3 = e2 + n3;
    double v = 0.0;
    for (int i = tid; i < e3; i += 256) {
        double w = (i < e0) ? w0 : (i < e1) ? w1 : (i < e2) ? w2 : w3;
        v += (double)P[i] * w;
    }
    for (int off = 32; off; off >>= 1) v += __shfl_down(v, off, 64);
    __shared__ double wsum[4];
    int lane = tid & 63, wid = tid >> 6;
    if (lane == 0) wsum[wid] = v;
    __syncthreads();
    if (tid == 0) out[0] = (float)(wsum[0] + wsum[1] + wsum[2] + wsum[3]);
}

extern "C" void kernel_launch(void* const* d_in, const int* in_sizes, int n_in,
                              void* d_out, int out_size, void* d_ws, size_t ws_size,
                              hipStream_t stream) {
    const float* Ii = (const float*)d_in[0];
    const float* Ir = (const float*)d_in[1];
    float* out = (float*)d_out;
    const int B = 16;

    // units = B * nstrips * nchunks, one wave per unit, 4 waves/block
    const int n0 = B * 9 * 64;   // 512x512, RC=8  -> 9216 waves (2304 blocks)
    const int n1 = B * 5 * 32;   // 256x256, RC=8  -> 2560 waves
    const int n2 = B * 3 * 16;   // 128x128, RC=8  -> 768 waves
    const int n3 = B * 2 * 8;    //  64x64,  RC=8  -> 256 waves

    char* ws = (char*)d_ws;
    float* P  = (float*)ws;                    // 12800 partials (pad to 16384)
    float* X1 = P + 16384;
    float* Y1 = X1 + B * 256 * 256;
    float* X2 = Y1 + B * 256 * 256;
    float* Y2 = X2 + B * 128 * 128;
    float* X3 = Y2 + B * 128 * 128;
    float* Y3 = X3 + B * 64 * 64;

    gms_scale_kernel<true,  true,  8><<<n0 / 4, 256, 0, stream>>>(Ii, Ir, 512, 512, 9, 64, P, X1, Y1);
    gms_scale_kernel<false, true,  8><<<n1 / 4, 256, 0, stream>>>(X1, Y1, 256, 256, 5, 32, P + n0, X2, Y2);
    gms_scale_kernel<false, true,  8><<<n2 / 4, 256, 0, stream>>>(X2, Y2, 128, 128, 3, 16, P + n0 + n1, X3, Y3);
    gms_scale_kernel<false, false, 8><<<n3 / 4, 256, 0, stream>>>(X3, Y3, 64, 64, 2, 8, P + n0 + n1 + n2, nullptr, nullptr);

    finalize_kernel<<<1, 256, 0, stream>>>(P, n0, n1, n2, n3, out);
}